// Round 9
// baseline (758.916 us; speedup 1.0000x reference)
//
#include <hip/hip_runtime.h>
#include <cmath>

#define NN 200000
#define EE 6400000
#define NBKT 391          // ceil(200000 / 512), bucket = col >> 9
#define GRID_A 512        // blocks in phase-A kernels (MUST match scan width)
#define BLK_A 256
#define RB_SHIFT 13       // row band = row >> 13 (8192 rows/band; y1 slice 0.79 MB, L2-fit)
#define NRB 25            // ceil(200000 / 8192)

// monotone float<->uint encoding: enc preserves order under unsigned max.
// Inter-layer y buffers are stored PRE-ENCODED: the gather hot loop does zero
// per-edge encode VALU; guarded LDS atomicMax on raw loaded words.
__device__ __forceinline__ unsigned int fenc(float f) {
    unsigned int u = __float_as_uint(f);
    return (u & 0x80000000u) ? ~u : (u | 0x80000000u);
}
__device__ __forceinline__ float fdec(unsigned int u) {
    unsigned int v = (u & 0x80000000u) ? (u & 0x7FFFFFFFu) : ~u;
    return __uint_as_float(v);
}

// =============== Phase A: bucket edges by col>>9 (counting sort, LDS atomics only) ===============

__global__ __launch_bounds__(BLK_A) void count_buckets_kernel(const int* __restrict__ col,
                                                              int* __restrict__ blkhist) {
    __shared__ int h[NBKT];
    for (int t = threadIdx.x; t < NBKT; t += BLK_A) h[t] = 0;
    __syncthreads();
    const int4* col4 = (const int4*)col;
    for (int i = blockIdx.x * BLK_A + threadIdx.x; i < EE / 4; i += GRID_A * BLK_A) {
        int4 c = col4[i];
        atomicAdd(&h[c.x >> 9], 1);
        atomicAdd(&h[c.y >> 9], 1);
        atomicAdd(&h[c.z >> 9], 1);
        atomicAdd(&h[c.w >> 9], 1);
    }
    __syncthreads();
    for (int t = threadIdx.x; t < NBKT; t += BLK_A) blkhist[blockIdx.x * NBKT + t] = h[t];
}

__global__ __launch_bounds__(GRID_A) void scan_cols_kernel(int* __restrict__ blkhist,
                                                           int* __restrict__ btot) {
    __shared__ int sc[GRID_A];
    int bkt = blockIdx.x, t = threadIdx.x;
    int v = blkhist[t * NBKT + bkt];
    sc[t] = v;
    __syncthreads();
    for (int off = 1; off < GRID_A; off <<= 1) {
        int add = (t >= off) ? sc[t - off] : 0;
        __syncthreads();
        sc[t] += add;
        __syncthreads();
    }
    blkhist[t * NBKT + bkt] = sc[t] - v;  // exclusive along blocks
    if (t == GRID_A - 1) btot[bkt] = sc[t];
}

__global__ __launch_bounds__(512) void scan_btot_kernel(const int* __restrict__ btot,
                                                        int* __restrict__ bbase) {
    __shared__ int sc[512];
    int t = threadIdx.x;
    int v = (t < NBKT) ? btot[t] : 0;
    sc[t] = v;
    __syncthreads();
    for (int off = 1; off < 512; off <<= 1) {
        int add = (t >= off) ? sc[t - off] : 0;
        __syncthreads();
        sc[t] += add;
        __syncthreads();
    }
    if (t < NBKT) bbase[t] = sc[t] - v;
    if (t == NBKT - 1) bbase[NBKT] = sc[t];  // total = EE
}

// A3: place packed codes (int4 edge loads). code = (col&511)<<18 | row  (row < 2^18)
__global__ __launch_bounds__(BLK_A) void place_pairs_kernel(const int* __restrict__ row,
                                                            const int* __restrict__ col,
                                                            const int* __restrict__ blkhist,
                                                            const int* __restrict__ bbase,
                                                            unsigned int* __restrict__ pairs) {
    __shared__ int cur[NBKT];
    for (int t = threadIdx.x; t < NBKT; t += BLK_A)
        cur[t] = bbase[t] + blkhist[blockIdx.x * NBKT + t];
    __syncthreads();
    const int4* col4 = (const int4*)col;
    const int4* row4 = (const int4*)row;
    for (int i = blockIdx.x * BLK_A + threadIdx.x; i < EE / 4; i += GRID_A * BLK_A) {
        int4 c = col4[i];
        int4 r = row4[i];
        int p0 = atomicAdd(&cur[c.x >> 9], 1);
        pairs[p0] = (unsigned int)r.x | ((unsigned int)(c.x & 511) << 18);
        int p1 = atomicAdd(&cur[c.y >> 9], 1);
        pairs[p1] = (unsigned int)r.y | ((unsigned int)(c.y & 511) << 18);
        int p2 = atomicAdd(&cur[c.z >> 9], 1);
        pairs[p2] = (unsigned int)r.z | ((unsigned int)(c.z & 511) << 18);
        int p3 = atomicAdd(&cur[c.w >> 9], 1);
        pairs[p3] = (unsigned int)r.w | ((unsigned int)(c.w & 511) << 18);
    }
}

// A4: per-bucket counting sort into BAND-MAJOR order (band = row>>RB_SHIFT).
__global__ __launch_bounds__(512) void bucket_build_band_kernel(const unsigned int* __restrict__ pairs,
                                                                const int* __restrict__ bbase,
                                                                float* __restrict__ dinv,
                                                                unsigned int* __restrict__ codes,
                                                                int* __restrict__ bandoffs) {
    __shared__ int bin[512 * NRB];   // flat band-major: linear n = bb*512 + lc
    __shared__ int sc[512];
    int b = blockIdx.x, tid = threadIdx.x;
    int base = bbase[b], end = bbase[b + 1];
    int node0 = b << 9;
    int nloc = NN - node0; if (nloc > 512) nloc = 512;

    for (int t = tid; t < 512 * NRB; t += 512) bin[t] = 0;
    __syncthreads();
    for (int i = base + tid; i < end; i += 512) {
        unsigned int p = pairs[i];
        int lc = p >> 18;
        int rw = (int)(p & 0x3FFFFu);
        atomicAdd(&bin[(rw >> RB_SHIFT) * 512 + lc], 1);
    }
    __syncthreads();

    // degree -> dinv (read before positions overwrite bins)
    if (tid < nloc) {
        int d = 0;
#pragma unroll
        for (int bb = 0; bb < NRB; ++bb) d += bin[bb * 512 + tid];
        dinv[node0 + tid] = rsqrtf((float)(d + 1));  // +1 self loop
    }
    __syncthreads();

    // exclusive scan of the flat array: thread t owns linear chunk [t*NRB, t*NRB+NRB)
    int tot = 0;
#pragma unroll
    for (int i = 0; i < NRB; ++i) tot += bin[tid * NRB + i];
    sc[tid] = tot;
    __syncthreads();
    for (int off = 1; off < 512; off <<= 1) {
        int add = (tid >= off) ? sc[tid - off] : 0;
        __syncthreads();
        sc[tid] += add;
        __syncthreads();
    }
    int run = base + sc[tid] - tot;   // global exclusive base of this chunk
#pragma unroll
    for (int i = 0; i < NRB; ++i) {
        int c = bin[tid * NRB + i];
        bin[tid * NRB + i] = run;     // becomes placement cursor
        run += c;
    }
    __syncthreads();

    if (tid < NRB) bandoffs[b * (NRB + 1) + tid] = bin[tid * 512];
    if (tid == 0) bandoffs[b * (NRB + 1) + NRB] = end;
    __syncthreads();

    for (int i = base + tid; i < end; i += 512) {
        unsigned int p = pairs[i];
        int lc = p >> 18;
        int rw = (int)(p & 0x3FFFFu);
        int pos = atomicAdd(&bin[(rw >> RB_SHIFT) * 512 + lc], 1);
        codes[pos] = p;
    }
}

// =============== layer-1 matmul, epilogue premultiplies dinv AND ENCODES: y = fenc(dinv*(x@W)) =======
__global__ void matmul128_y_kernel(const float* __restrict__ x, const float* __restrict__ W,
                                   const float* __restrict__ dinv, unsigned int* __restrict__ y, int n) {
    __shared__ float Ws[128 * 24];
    for (int t = threadIdx.x; t < 128 * 24; t += blockDim.x) Ws[t] = W[t];
    __syncthreads();
    int i = blockIdx.x * blockDim.x + threadIdx.x;
    if (i >= n) return;
    float acc[24];
#pragma unroll
    for (int j = 0; j < 24; ++j) acc[j] = 0.f;
    const float4* hr = (const float4*)(x + (size_t)i * 128);
#pragma unroll 8
    for (int k4 = 0; k4 < 32; ++k4) {
        float4 hv = hr[k4];
        const float* wk = &Ws[k4 * 4 * 24];
#pragma unroll
        for (int j = 0; j < 24; ++j) acc[j] += hv.x * wk[j];
#pragma unroll
        for (int j = 0; j < 24; ++j) acc[j] += hv.y * wk[24 + j];
#pragma unroll
        for (int j = 0; j < 24; ++j) acc[j] += hv.z * wk[48 + j];
#pragma unroll
        for (int j = 0; j < 24; ++j) acc[j] += hv.w * wk[72 + j];
    }
    float di = dinv[i];
    uint4* orow = (uint4*)(y + (size_t)i * 24);
#pragma unroll
    for (int q = 0; q < 6; ++q) {
        uint4 o;
        o.x = fenc(di * acc[q * 4 + 0]);
        o.y = fenc(di * acc[q * 4 + 1]);
        o.z = fenc(di * acc[q * 4 + 2]);
        o.w = fenc(di * acc[q * 4 + 3]);
        orow[q] = o;
    }
}

// =============== band-phased bucket gather, LANE-GROUP-PER-EDGE for address coalescing ==============
// One block per 512-node bucket; fully co-resident band sweep (r4-r8 structure).
// For DOUT>=6 each edge is handled by G lanes (G=8 for 24, G=4 for 12/6): lane j
// loads chunk j of the source row, so a wave's gather instruction covers whole
// rows of consecutive edges -> ~2.3 unique cachelines/edge instead of 6 (the
// r8 bottleneck: TA address processing, ~150K lane-addrs/CU). Guarded atomics
// (r6 lesson) and odd LDS stride (r5 lesson) unchanged.
template<int DOUT, int DNEXT, bool FINAL>
__global__ __launch_bounds__(512) void gather_band_kernel(const unsigned int* __restrict__ codes,
                                                          const int* __restrict__ bandoffs,
                                                          const float* __restrict__ dinv,
                                                          const unsigned int* __restrict__ y,  // encoded
                                                          const float* __restrict__ bias,
                                                          const float* __restrict__ Wn,
                                                          const float* __restrict__ bcls,
                                                          float* __restrict__ outp,   // encoded when !FINAL
                                                          float* __restrict__ hout) {
    constexpr int ST = DOUT + 1;           // odd stride -> conflict-free random access
    constexpr int G  = (DOUT == 24) ? 8 : (DOUT == 12 || DOUT == 6) ? 4 : 1;  // lanes per edge
    constexpr bool U4 = (DOUT % 4 == 0);   // chunk type: uint4 else uint2
    constexpr int CW = U4 ? 4 : 2;         // words per chunk
    constexpr int CH = DOUT / CW;          // chunks per row
    __shared__ unsigned int acc[512 * ST];
    __shared__ float dcs[512];
    __shared__ float Ws[DOUT * DNEXT];
    __shared__ float bs[DOUT];
    const int b0 = blockIdx.x;
    const int node0 = b0 << 9;
    const int nloc = (NN - node0 < 512) ? (NN - node0) : 512;
    const int tid = threadIdx.x;

    if (tid < DOUT * DNEXT) Ws[tid] = Wn[tid];
    if (tid < DOUT) bs[tid] = bias[tid];
    if (tid < nloc) dcs[tid] = dinv[node0 + tid];
    for (int idx = tid; idx < nloc * DOUT; idx += 512) {
        int lc = idx / DOUT;
        int f  = idx - lc * DOUT;
        acc[lc * ST + f] = y[(size_t)node0 * DOUT + idx];   // self-loop seed (already encoded)
    }
    __syncthreads();

    const int* bo = bandoffs + b0 * (NRB + 1);

    if constexpr (G > 1) {
        const int g = tid / G;             // edge-group id within block
        const int j = tid % G;             // chunk role within edge
        constexpr int NG = 512 / G;        // edge groups per block
#pragma unroll 1
        for (int bb = 0; bb < NRB; ++bb) {
            const int e = bo[bb + 1];
            int i = bo[bb] + g;
            for (; i + NG < e; i += 2 * NG) {   // 2 edges in flight per lane
                unsigned int p0 = codes[i];
                unsigned int p1 = codes[i + NG];
                size_t r0 = (size_t)(p0 & 0x3FFFFu);
                size_t r1 = (size_t)(p1 & 0x3FFFFu);
                if constexpr (U4) {
                    uint4 c0, c1;
                    if (j < CH) {
                        c0 = *(const uint4*)(y + r0 * DOUT + j * 4);
                        c1 = *(const uint4*)(y + r1 * DOUT + j * 4);
                        unsigned int* a0 = &acc[(p0 >> 18) * ST + j * 4];
                        if (c0.x > a0[0]) atomicMax(&a0[0], c0.x);
                        if (c0.y > a0[1]) atomicMax(&a0[1], c0.y);
                        if (c0.z > a0[2]) atomicMax(&a0[2], c0.z);
                        if (c0.w > a0[3]) atomicMax(&a0[3], c0.w);
                        unsigned int* a1 = &acc[(p1 >> 18) * ST + j * 4];
                        if (c1.x > a1[0]) atomicMax(&a1[0], c1.x);
                        if (c1.y > a1[1]) atomicMax(&a1[1], c1.y);
                        if (c1.z > a1[2]) atomicMax(&a1[2], c1.z);
                        if (c1.w > a1[3]) atomicMax(&a1[3], c1.w);
                    }
                } else {
                    uint2 c0, c1;
                    if (j < CH) {
                        c0 = *(const uint2*)(y + r0 * DOUT + j * 2);
                        c1 = *(const uint2*)(y + r1 * DOUT + j * 2);
                        unsigned int* a0 = &acc[(p0 >> 18) * ST + j * 2];
                        if (c0.x > a0[0]) atomicMax(&a0[0], c0.x);
                        if (c0.y > a0[1]) atomicMax(&a0[1], c0.y);
                        unsigned int* a1 = &acc[(p1 >> 18) * ST + j * 2];
                        if (c1.x > a1[0]) atomicMax(&a1[0], c1.x);
                        if (c1.y > a1[1]) atomicMax(&a1[1], c1.y);
                    }
                }
            }
            if (i < e) {
                unsigned int p0 = codes[i];
                size_t r0 = (size_t)(p0 & 0x3FFFFu);
                if constexpr (U4) {
                    if (j < CH) {
                        uint4 c0 = *(const uint4*)(y + r0 * DOUT + j * 4);
                        unsigned int* a0 = &acc[(p0 >> 18) * ST + j * 4];
                        if (c0.x > a0[0]) atomicMax(&a0[0], c0.x);
                        if (c0.y > a0[1]) atomicMax(&a0[1], c0.y);
                        if (c0.z > a0[2]) atomicMax(&a0[2], c0.z);
                        if (c0.w > a0[3]) atomicMax(&a0[3], c0.w);
                    }
                } else {
                    if (j < CH) {
                        uint2 c0 = *(const uint2*)(y + r0 * DOUT + j * 2);
                        unsigned int* a0 = &acc[(p0 >> 18) * ST + j * 2];
                        if (c0.x > a0[0]) atomicMax(&a0[0], c0.x);
                        if (c0.y > a0[1]) atomicMax(&a0[1], c0.y);
                    }
                }
            }
            __syncthreads();   // band phase barrier
        }
    } else {
        // per-lane path for small DOUT (4, 2): one row = 1 line already
#pragma unroll 1
        for (int bb = 0; bb < NRB; ++bb) {
            const int e = bo[bb + 1];
            for (int i = bo[bb] + tid; i < e; i += 1024) {
                const int i2 = i + 512;
                const bool two = (i2 < e);
                unsigned int p0 = codes[i];
                size_t r0 = (size_t)(p0 & 0x3FFFFu);
                unsigned int* a0 = &acc[(p0 >> 18) * ST];
                unsigned int p1 = 0; unsigned int* a1 = nullptr;
                if constexpr (U4) {
                    uint4 c0, c1;
                    c0 = *(const uint4*)(y + r0 * DOUT);
                    if (two) {
                        p1 = codes[i2];
                        c1 = *(const uint4*)(y + (size_t)(p1 & 0x3FFFFu) * DOUT);
                        a1 = &acc[(p1 >> 18) * ST];
                    }
                    if (c0.x > a0[0]) atomicMax(&a0[0], c0.x);
                    if (c0.y > a0[1]) atomicMax(&a0[1], c0.y);
                    if (c0.z > a0[2]) atomicMax(&a0[2], c0.z);
                    if (c0.w > a0[3]) atomicMax(&a0[3], c0.w);
                    if (two) {
                        if (c1.x > a1[0]) atomicMax(&a1[0], c1.x);
                        if (c1.y > a1[1]) atomicMax(&a1[1], c1.y);
                        if (c1.z > a1[2]) atomicMax(&a1[2], c1.z);
                        if (c1.w > a1[3]) atomicMax(&a1[3], c1.w);
                    }
                } else {
                    uint2 c0, c1;
                    c0 = *(const uint2*)(y + r0 * DOUT);
                    if (two) {
                        p1 = codes[i2];
                        c1 = *(const uint2*)(y + (size_t)(p1 & 0x3FFFFu) * DOUT);
                        a1 = &acc[(p1 >> 18) * ST];
                    }
                    if (c0.x > a0[0]) atomicMax(&a0[0], c0.x);
                    if (c0.y > a0[1]) atomicMax(&a0[1], c0.y);
                    if (two) {
                        if (c1.x > a1[0]) atomicMax(&a1[0], c1.x);
                        if (c1.y > a1[1]) atomicMax(&a1[1], c1.y);
                    }
                }
            }
            __syncthreads();
        }
    }

    // decode + tanh in place (float bits through the same padded layout)
    float* hsf = (float*)acc;
    for (int idx = tid; idx < nloc * DOUT; idx += 512) {
        int lc = idx / DOUT;
        int f  = idx - lc * DOUT;
        hsf[lc * ST + f] = tanhf(dcs[lc] * fdec(acc[lc * ST + f]) + bs[f]);
    }
    __syncthreads();

    if constexpr (!FINAL) {
        unsigned int* outu = (unsigned int*)outp;
        for (int idx = tid; idx < nloc * DNEXT; idx += 512) {
            int lc = idx / DNEXT;
            int j = idx - lc * DNEXT;
            float a = 0.f;
#pragma unroll
            for (int k = 0; k < DOUT; ++k) a += hsf[lc * ST + k] * Ws[k * DNEXT + j];
            outu[(size_t)node0 * DNEXT + idx] = fenc(dcs[lc] * a);
        }
    } else {
        for (int lc = tid; lc < nloc; lc += 512) {
            float h0 = hsf[lc * ST], h1 = hsf[lc * ST + 1];
            float2 ho; ho.x = h0; ho.y = h1;
            ((float2*)hout)[node0 + lc] = ho;
            float4 o;
            o.x = h0 * Ws[0] + h1 * Ws[DNEXT + 0] + bcls[0];
            o.y = h0 * Ws[1] + h1 * Ws[DNEXT + 1] + bcls[1];
            o.z = h0 * Ws[2] + h1 * Ws[DNEXT + 2] + bcls[2];
            o.w = h0 * Ws[3] + h1 * Ws[DNEXT + 3] + bcls[3];
            ((float4*)outp)[node0 + lc] = o;
        }
    }
}

extern "C" void kernel_launch(void* const* d_in, const int* in_sizes, int n_in,
                              void* d_out, int out_size, void* d_ws, size_t ws_size,
                              hipStream_t stream) {
    const float* x  = (const float*)d_in[0];
    const int*   ei = (const int*)d_in[1];
    const int* row = ei;            // edge_index[0] = source
    const int* col = ei + EE;       // edge_index[1] = target
    const float* W1 = (const float*)d_in[2];  const float* b1 = (const float*)d_in[3];
    const float* W2 = (const float*)d_in[4];  const float* b2 = (const float*)d_in[5];
    const float* W3 = (const float*)d_in[6];  const float* b3 = (const float*)d_in[7];
    const float* W4 = (const float*)d_in[8];  const float* b4 = (const float*)d_in[9];
    const float* W5 = (const float*)d_in[10]; const float* b5 = (const float*)d_in[11];
    const float* Wc = (const float*)d_in[12]; const float* bc = (const float*)d_in[13];
    float* out = (float*)d_out;

    // ---- workspace carve (identical to r4-r8, tripwire-proven) ----
    // pairs is dead before matmul128_y writes bufB -> alias them. codes persists all layers.
    char* ws = (char*)d_ws;
    float*        dinv       = (float*)(ws + 0);             //    800,000
    int*          bandoffs   = (int*)(ws + 800000);          //     40,664 (NBKT*(NRB+1) ints) -> pad 40,960
    int*          bbase      = (int*)(ws + 840960);          //      2,048
    int*          btot       = (int*)(ws + 843008);          //      2,048
    int*          blkhist    = (int*)(ws + 845056);          //    802,816  (GRID_A*NBKT ints)
    unsigned int* codes      = (unsigned int*)(ws + 1647872);   // 25,600,000
    unsigned int* pairs      = (unsigned int*)(ws + 27247872);  // 25,600,000
    unsigned int* bufB       = (unsigned int*)(ws + 27247872);  // 25,600,000 (aliases pairs; y1/y3/y5, ENCODED)
    unsigned int* bufA       = (unsigned int*)(ws + 52847872);  // 19,200,000 (y2/y4, ENCODED)
    // total: 72,047,872 B

    const int BLK = 256;
    const int gN = (NN + BLK - 1) / BLK;       // 782

    // ---- CSR build: two-level counting sort; adjacency emitted band-major per bucket ----
    count_buckets_kernel<<<GRID_A, BLK_A, 0, stream>>>(col, blkhist);
    scan_cols_kernel<<<NBKT, GRID_A, 0, stream>>>(blkhist, btot);
    scan_btot_kernel<<<1, 512, 0, stream>>>(btot, bbase);
    place_pairs_kernel<<<GRID_A, BLK_A, 0, stream>>>(row, col, blkhist, bbase, pairs);
    bucket_build_band_kernel<<<NBKT, 512, 0, stream>>>(pairs, bbase, dinv, codes, bandoffs);

    // ---- layer 1 matmul: y1 = fenc(dinv * (x @ W1)), [N,24] encoded ----
    matmul128_y_kernel<<<gN, BLK, 0, stream>>>(x, W1, dinv, bufB, NN);

    // ---- layer 1 gather + layer-2 matmul fused: y2 [N,12] encoded ----
    gather_band_kernel<24, 12, false><<<NBKT, 512, 0, stream>>>(
        codes, bandoffs, dinv, bufB, b1, W2, nullptr, (float*)bufA, nullptr);
    // ---- layer 2 gather + layer-3 matmul fused: y3 [N,6] encoded ----
    gather_band_kernel<12, 6, false><<<NBKT, 512, 0, stream>>>(
        codes, bandoffs, dinv, bufA, b2, W3, nullptr, (float*)bufB, nullptr);
    // ---- layer 3 gather + layer-4 matmul fused: y4 [N,4] encoded ----
    gather_band_kernel<6, 4, false><<<NBKT, 512, 0, stream>>>(
        codes, bandoffs, dinv, bufB, b3, W4, nullptr, (float*)bufA, nullptr);
    // ---- layer 4 gather + layer-5 matmul fused: y5 [N,2] encoded ----
    gather_band_kernel<4, 2, false><<<NBKT, 512, 0, stream>>>(
        codes, bandoffs, dinv, bufA, b4, W5, nullptr, (float*)bufB, nullptr);
    // ---- layer 5 gather + classifier fused: out [N,4], h [N,2] (plain floats) ----
    gather_band_kernel<2, 4, true><<<NBKT, 512, 0, stream>>>(
        codes, bandoffs, dinv, bufB, b5, Wc, bc, out, out + (size_t)NN * 4);
}

// Round 10
// 657.016 us; speedup vs baseline: 1.1551x; 1.1551x over previous
//
#include <hip/hip_runtime.h>
#include <cmath>

#define NN 200000
#define EE 6400000
#define CSH 8             // bucket = col >> 8 (256 nodes/bucket)
#define BSZ 256           // nodes per bucket
#define NBKT 782          // ceil(200000 / 256)
#define GRID_A 512        // blocks in phase-A kernels (MUST match scan width)
#define BLK_A 256
#define RB_SHIFT 13       // row band = row >> 13 (8192 rows/band; y1 slice 0.79 MB, L2-fit)
#define NRB 25            // ceil(200000 / 8192)

// monotone float<->uint encoding: enc preserves order under unsigned max.
// Inter-layer y buffers are stored PRE-ENCODED: the gather hot loop does zero
// per-edge encode VALU; guarded LDS atomicMax on raw loaded words.
__device__ __forceinline__ unsigned int fenc(float f) {
    unsigned int u = __float_as_uint(f);
    return (u & 0x80000000u) ? ~u : (u | 0x80000000u);
}
__device__ __forceinline__ float fdec(unsigned int u) {
    unsigned int v = (u & 0x80000000u) ? (u & 0x7FFFFFFFu) : ~u;
    return __uint_as_float(v);
}

// =============== Phase A: bucket edges by col>>CSH (counting sort, LDS atomics only) ===============

__global__ __launch_bounds__(BLK_A) void count_buckets_kernel(const int* __restrict__ col,
                                                              int* __restrict__ blkhist) {
    __shared__ int h[NBKT];
    for (int t = threadIdx.x; t < NBKT; t += BLK_A) h[t] = 0;
    __syncthreads();
    const int4* col4 = (const int4*)col;
    for (int i = blockIdx.x * BLK_A + threadIdx.x; i < EE / 4; i += GRID_A * BLK_A) {
        int4 c = col4[i];
        atomicAdd(&h[c.x >> CSH], 1);
        atomicAdd(&h[c.y >> CSH], 1);
        atomicAdd(&h[c.z >> CSH], 1);
        atomicAdd(&h[c.w >> CSH], 1);
    }
    __syncthreads();
    for (int t = threadIdx.x; t < NBKT; t += BLK_A) blkhist[blockIdx.x * NBKT + t] = h[t];
}

__global__ __launch_bounds__(GRID_A) void scan_cols_kernel(int* __restrict__ blkhist,
                                                           int* __restrict__ btot) {
    __shared__ int sc[GRID_A];
    int bkt = blockIdx.x, t = threadIdx.x;
    int v = blkhist[t * NBKT + bkt];
    sc[t] = v;
    __syncthreads();
    for (int off = 1; off < GRID_A; off <<= 1) {
        int add = (t >= off) ? sc[t - off] : 0;
        __syncthreads();
        sc[t] += add;
        __syncthreads();
    }
    blkhist[t * NBKT + bkt] = sc[t] - v;  // exclusive along blocks
    if (t == GRID_A - 1) btot[bkt] = sc[t];
}

__global__ __launch_bounds__(1024) void scan_btot_kernel(const int* __restrict__ btot,
                                                         int* __restrict__ bbase) {
    __shared__ int sc[1024];
    int t = threadIdx.x;
    int v = (t < NBKT) ? btot[t] : 0;
    sc[t] = v;
    __syncthreads();
    for (int off = 1; off < 1024; off <<= 1) {
        int add = (t >= off) ? sc[t - off] : 0;
        __syncthreads();
        sc[t] += add;
        __syncthreads();
    }
    if (t < NBKT) bbase[t] = sc[t] - v;
    if (t == NBKT - 1) bbase[NBKT] = sc[t];  // total = EE
}

// A3: place packed codes (int4 edge loads). code = (col&255)<<18 | row  (row < 2^18)
__global__ __launch_bounds__(BLK_A) void place_pairs_kernel(const int* __restrict__ row,
                                                            const int* __restrict__ col,
                                                            const int* __restrict__ blkhist,
                                                            const int* __restrict__ bbase,
                                                            unsigned int* __restrict__ pairs) {
    __shared__ int cur[NBKT];
    for (int t = threadIdx.x; t < NBKT; t += BLK_A)
        cur[t] = bbase[t] + blkhist[blockIdx.x * NBKT + t];
    __syncthreads();
    const int4* col4 = (const int4*)col;
    const int4* row4 = (const int4*)row;
    for (int i = blockIdx.x * BLK_A + threadIdx.x; i < EE / 4; i += GRID_A * BLK_A) {
        int4 c = col4[i];
        int4 r = row4[i];
        int p0 = atomicAdd(&cur[c.x >> CSH], 1);
        pairs[p0] = (unsigned int)r.x | ((unsigned int)(c.x & (BSZ - 1)) << 18);
        int p1 = atomicAdd(&cur[c.y >> CSH], 1);
        pairs[p1] = (unsigned int)r.y | ((unsigned int)(c.y & (BSZ - 1)) << 18);
        int p2 = atomicAdd(&cur[c.z >> CSH], 1);
        pairs[p2] = (unsigned int)r.z | ((unsigned int)(c.z & (BSZ - 1)) << 18);
        int p3 = atomicAdd(&cur[c.w >> CSH], 1);
        pairs[p3] = (unsigned int)r.w | ((unsigned int)(c.w & (BSZ - 1)) << 18);
    }
}

// A4: per-bucket counting sort into BAND-MAJOR order (band = row>>RB_SHIFT).
__global__ __launch_bounds__(512) void bucket_build_band_kernel(const unsigned int* __restrict__ pairs,
                                                                const int* __restrict__ bbase,
                                                                float* __restrict__ dinv,
                                                                unsigned int* __restrict__ codes,
                                                                int* __restrict__ bandoffs) {
    __shared__ int bin[BSZ * NRB];   // 6400: flat band-major, linear n = bb*BSZ + lc
    __shared__ int sc[512];
    int b = blockIdx.x, tid = threadIdx.x;
    int base = bbase[b], end = bbase[b + 1];
    int node0 = b << CSH;
    int nloc = NN - node0; if (nloc > BSZ) nloc = BSZ;

    for (int t = tid; t < BSZ * NRB; t += 512) bin[t] = 0;
    __syncthreads();
    for (int i = base + tid; i < end; i += 512) {
        unsigned int p = pairs[i];
        int lc = p >> 18;
        int rw = (int)(p & 0x3FFFFu);
        atomicAdd(&bin[(rw >> RB_SHIFT) * BSZ + lc], 1);
    }
    __syncthreads();

    // degree -> dinv (read before positions overwrite bins)
    if (tid < nloc) {
        int d = 0;
#pragma unroll
        for (int bb = 0; bb < NRB; ++bb) d += bin[bb * BSZ + tid];
        dinv[node0 + tid] = rsqrtf((float)(d + 1));  // +1 self loop
    }
    __syncthreads();

    // exclusive scan of the flat 6400 array: thread t<BSZ owns chunk [t*NRB, t*NRB+NRB)
    int tot = 0;
    if (tid < BSZ) {
#pragma unroll
        for (int i = 0; i < NRB; ++i) tot += bin[tid * NRB + i];
    }
    sc[tid] = tot;
    __syncthreads();
    for (int off = 1; off < 512; off <<= 1) {
        int add = (tid >= off) ? sc[tid - off] : 0;
        __syncthreads();
        sc[tid] += add;
        __syncthreads();
    }
    if (tid < BSZ) {
        int run = base + sc[tid] - tot;   // global exclusive base of this chunk
#pragma unroll
        for (int i = 0; i < NRB; ++i) {
            int c = bin[tid * NRB + i];
            bin[tid * NRB + i] = run;     // becomes placement cursor
            run += c;
        }
    }
    __syncthreads();

    if (tid < NRB) bandoffs[b * (NRB + 1) + tid] = bin[tid * BSZ];
    if (tid == 0) bandoffs[b * (NRB + 1) + NRB] = end;
    __syncthreads();

    for (int i = base + tid; i < end; i += 512) {
        unsigned int p = pairs[i];
        int lc = p >> 18;
        int rw = (int)(p & 0x3FFFFu);
        int pos = atomicAdd(&bin[(rw >> RB_SHIFT) * BSZ + lc], 1);
        codes[pos] = p;
    }
}

// =============== layer-1 matmul, epilogue premultiplies dinv AND ENCODES: y = fenc(dinv*(x@W)) =======
__global__ void matmul128_y_kernel(const float* __restrict__ x, const float* __restrict__ W,
                                   const float* __restrict__ dinv, unsigned int* __restrict__ y, int n) {
    __shared__ float Ws[128 * 24];
    for (int t = threadIdx.x; t < 128 * 24; t += blockDim.x) Ws[t] = W[t];
    __syncthreads();
    int i = blockIdx.x * blockDim.x + threadIdx.x;
    if (i >= n) return;
    float acc[24];
#pragma unroll
    for (int j = 0; j < 24; ++j) acc[j] = 0.f;
    const float4* hr = (const float4*)(x + (size_t)i * 128);
#pragma unroll 8
    for (int k4 = 0; k4 < 32; ++k4) {
        float4 hv = hr[k4];
        const float* wk = &Ws[k4 * 4 * 24];
#pragma unroll
        for (int j = 0; j < 24; ++j) acc[j] += hv.x * wk[j];
#pragma unroll
        for (int j = 0; j < 24; ++j) acc[j] += hv.y * wk[24 + j];
#pragma unroll
        for (int j = 0; j < 24; ++j) acc[j] += hv.z * wk[48 + j];
#pragma unroll
        for (int j = 0; j < 24; ++j) acc[j] += hv.w * wk[72 + j];
    }
    float di = dinv[i];
    uint4* orow = (uint4*)(y + (size_t)i * 24);
#pragma unroll
    for (int q = 0; q < 6; ++q) {
        uint4 o;
        o.x = fenc(di * acc[q * 4 + 0]);
        o.y = fenc(di * acc[q * 4 + 1]);
        o.z = fenc(di * acc[q * 4 + 2]);
        o.w = fenc(di * acc[q * 4 + 3]);
        orow[q] = o;
    }
}

// =============== band-phased bucket gather on PRE-ENCODED y: GUARDED ds_max_u32 ======================
// 256-node buckets: 782 blocks x 512 threads, ~27 KB LDS -> 3-4 blocks/CU, ALL
// co-resident (band lockstep preserved), ~24 waves/CU in flight (r8 was 1.53
// blocks/CU, 33% occupancy, latency-bound). Hot loop identical to r8: guarded
// atomics (r6 lesson), odd per-node stride (r5), pre-encoded y (r8), per-lane
// whole-row gather (r9 lane-split reverted).
template<int DOUT, int DNEXT, bool FINAL>
__global__ __launch_bounds__(512) void gather_band_kernel(const unsigned int* __restrict__ codes,
                                                          const int* __restrict__ bandoffs,
                                                          const float* __restrict__ dinv,
                                                          const unsigned int* __restrict__ y,  // encoded
                                                          const float* __restrict__ bias,
                                                          const float* __restrict__ Wn,
                                                          const float* __restrict__ bcls,
                                                          float* __restrict__ outp,   // encoded when !FINAL
                                                          float* __restrict__ hout) {
    constexpr int ST = DOUT + 1;           // odd stride -> conflict-free random access
    __shared__ unsigned int acc[BSZ * ST];
    __shared__ float dcs[BSZ];
    __shared__ float Ws[DOUT * DNEXT];
    __shared__ float bs[DOUT];
    const int b0 = blockIdx.x;
    const int node0 = b0 << CSH;
    const int nloc = (NN - node0 < BSZ) ? (NN - node0) : BSZ;
    const int tid = threadIdx.x;

    if (tid < DOUT * DNEXT) Ws[tid] = Wn[tid];
    if (tid < DOUT) bs[tid] = bias[tid];
    if (tid < nloc) dcs[tid] = dinv[node0 + tid];
    for (int idx = tid; idx < nloc * DOUT; idx += 512) {
        int lc = idx / DOUT;
        int f  = idx - lc * DOUT;
        acc[lc * ST + f] = y[(size_t)node0 * DOUT + idx];   // self-loop seed (already encoded)
    }
    __syncthreads();

    const int* bo = bandoffs + b0 * (NRB + 1);
#pragma unroll 1
    for (int bb = 0; bb < NRB; ++bb) {
        const int e = bo[bb + 1];
        for (int i = bo[bb] + tid; i < e; i += 1024) {
            const int i2 = i + 512;
            const bool two = (i2 < e);
            unsigned int p0 = codes[i];
            size_t r0 = (size_t)(p0 & 0x3FFFFu);
            unsigned int* a0 = &acc[(p0 >> 18) * ST];
            unsigned int p1 = 0; unsigned int* a1 = nullptr;
            if constexpr (DOUT % 4 == 0) {
                constexpr int NQ = DOUT / 4;
                const uint4* y0 = (const uint4*)(y + r0 * DOUT);
                uint4 c0[NQ];
#pragma unroll
                for (int q = 0; q < NQ; ++q) c0[q] = y0[q];
                uint4 c1[NQ];
                if (two) {
                    p1 = codes[i2];
                    size_t r1 = (size_t)(p1 & 0x3FFFFu);
                    const uint4* y1 = (const uint4*)(y + r1 * DOUT);
#pragma unroll
                    for (int q = 0; q < NQ; ++q) c1[q] = y1[q];
                    a1 = &acc[(p1 >> 18) * ST];
                }
#pragma unroll
                for (int q = 0; q < NQ; ++q) {
                    if (c0[q].x > a0[q * 4 + 0]) atomicMax(&a0[q * 4 + 0], c0[q].x);
                    if (c0[q].y > a0[q * 4 + 1]) atomicMax(&a0[q * 4 + 1], c0[q].y);
                    if (c0[q].z > a0[q * 4 + 2]) atomicMax(&a0[q * 4 + 2], c0[q].z);
                    if (c0[q].w > a0[q * 4 + 3]) atomicMax(&a0[q * 4 + 3], c0[q].w);
                }
                if (two) {
#pragma unroll
                    for (int q = 0; q < NQ; ++q) {
                        if (c1[q].x > a1[q * 4 + 0]) atomicMax(&a1[q * 4 + 0], c1[q].x);
                        if (c1[q].y > a1[q * 4 + 1]) atomicMax(&a1[q * 4 + 1], c1[q].y);
                        if (c1[q].z > a1[q * 4 + 2]) atomicMax(&a1[q * 4 + 2], c1[q].z);
                        if (c1[q].w > a1[q * 4 + 3]) atomicMax(&a1[q * 4 + 3], c1[q].w);
                    }
                }
            } else {
                constexpr int NQ = DOUT / 2;
                const uint2* y0 = (const uint2*)(y + r0 * DOUT);
                uint2 c0[NQ];
#pragma unroll
                for (int q = 0; q < NQ; ++q) c0[q] = y0[q];
                uint2 c1[NQ];
                if (two) {
                    p1 = codes[i2];
                    size_t r1 = (size_t)(p1 & 0x3FFFFu);
                    const uint2* y1 = (const uint2*)(y + r1 * DOUT);
#pragma unroll
                    for (int q = 0; q < NQ; ++q) c1[q] = y1[q];
                    a1 = &acc[(p1 >> 18) * ST];
                }
#pragma unroll
                for (int q = 0; q < NQ; ++q) {
                    if (c0[q].x > a0[q * 2 + 0]) atomicMax(&a0[q * 2 + 0], c0[q].x);
                    if (c0[q].y > a0[q * 2 + 1]) atomicMax(&a0[q * 2 + 1], c0[q].y);
                }
                if (two) {
#pragma unroll
                    for (int q = 0; q < NQ; ++q) {
                        if (c1[q].x > a1[q * 2 + 0]) atomicMax(&a1[q * 2 + 0], c1[q].x);
                        if (c1[q].y > a1[q * 2 + 1]) atomicMax(&a1[q * 2 + 1], c1[q].y);
                    }
                }
            }
        }
        __syncthreads();   // keep the block (and, chip-wide, all co-resident blocks) in one band
    }

    // decode + tanh in place (float bits through the same padded layout)
    float* hsf = (float*)acc;
    for (int idx = tid; idx < nloc * DOUT; idx += 512) {
        int lc = idx / DOUT;
        int f  = idx - lc * DOUT;
        hsf[lc * ST + f] = tanhf(dcs[lc] * fdec(acc[lc * ST + f]) + bs[f]);
    }
    __syncthreads();

    if constexpr (!FINAL) {
        unsigned int* outu = (unsigned int*)outp;
        for (int idx = tid; idx < nloc * DNEXT; idx += 512) {
            int lc = idx / DNEXT;
            int j = idx - lc * DNEXT;
            float a = 0.f;
#pragma unroll
            for (int k = 0; k < DOUT; ++k) a += hsf[lc * ST + k] * Ws[k * DNEXT + j];
            outu[(size_t)node0 * DNEXT + idx] = fenc(dcs[lc] * a);
        }
    } else {
        for (int lc = tid; lc < nloc; lc += 512) {
            float h0 = hsf[lc * ST], h1 = hsf[lc * ST + 1];
            float2 ho; ho.x = h0; ho.y = h1;
            ((float2*)hout)[node0 + lc] = ho;
            float4 o;
            o.x = h0 * Ws[0] + h1 * Ws[DNEXT + 0] + bcls[0];
            o.y = h0 * Ws[1] + h1 * Ws[DNEXT + 1] + bcls[1];
            o.z = h0 * Ws[2] + h1 * Ws[DNEXT + 2] + bcls[2];
            o.w = h0 * Ws[3] + h1 * Ws[DNEXT + 3] + bcls[3];
            ((float4*)outp)[node0 + lc] = o;
        }
    }
}

extern "C" void kernel_launch(void* const* d_in, const int* in_sizes, int n_in,
                              void* d_out, int out_size, void* d_ws, size_t ws_size,
                              hipStream_t stream) {
    const float* x  = (const float*)d_in[0];
    const int*   ei = (const int*)d_in[1];
    const int* row = ei;            // edge_index[0] = source
    const int* col = ei + EE;       // edge_index[1] = target
    const float* W1 = (const float*)d_in[2];  const float* b1 = (const float*)d_in[3];
    const float* W2 = (const float*)d_in[4];  const float* b2 = (const float*)d_in[5];
    const float* W3 = (const float*)d_in[6];  const float* b3 = (const float*)d_in[7];
    const float* W4 = (const float*)d_in[8];  const float* b4 = (const float*)d_in[9];
    const float* W5 = (const float*)d_in[10]; const float* b5 = (const float*)d_in[11];
    const float* Wc = (const float*)d_in[12]; const float* bc = (const float*)d_in[13];
    float* out = (float*)d_out;

    // ---- workspace carve (72,889,344 B < 73,606,912 proven cap) ----
    // pairs is dead before matmul128_y writes bufB -> alias them. codes persists all layers.
    char* ws = (char*)d_ws;
    float*        dinv       = (float*)(ws + 0);                //    800,000
    int*          bandoffs   = (int*)(ws + 800000);             //     81,328 (NBKT*(NRB+1)) -> pad 81,408
    int*          bbase      = (int*)(ws + 881408);             //      3,132 -> pad 3,200
    int*          btot       = (int*)(ws + 884608);             //      3,128 -> pad 3,200
    int*          blkhist    = (int*)(ws + 887808);             //  1,601,536 (GRID_A*NBKT ints)
    unsigned int* codes      = (unsigned int*)(ws + 2489344);   // 25,600,000
    unsigned int* pairs      = (unsigned int*)(ws + 28089344);  // 25,600,000
    unsigned int* bufB       = (unsigned int*)(ws + 28089344);  // (aliases pairs; y1/y3/y5, ENCODED)
    unsigned int* bufA       = (unsigned int*)(ws + 53689344);  // 19,200,000 (y2/y4, ENCODED)
    // total: 72,889,344 B

    const int BLK = 256;
    const int gN = (NN + BLK - 1) / BLK;       // 782

    // ---- CSR build: two-level counting sort; adjacency emitted band-major per bucket ----
    count_buckets_kernel<<<GRID_A, BLK_A, 0, stream>>>(col, blkhist);
    scan_cols_kernel<<<NBKT, GRID_A, 0, stream>>>(blkhist, btot);
    scan_btot_kernel<<<1, 1024, 0, stream>>>(btot, bbase);
    place_pairs_kernel<<<GRID_A, BLK_A, 0, stream>>>(row, col, blkhist, bbase, pairs);
    bucket_build_band_kernel<<<NBKT, 512, 0, stream>>>(pairs, bbase, dinv, codes, bandoffs);

    // ---- layer 1 matmul: y1 = fenc(dinv * (x @ W1)), [N,24] encoded ----
    matmul128_y_kernel<<<gN, BLK, 0, stream>>>(x, W1, dinv, bufB, NN);

    // ---- layer 1 gather + layer-2 matmul fused: y2 [N,12] encoded ----
    gather_band_kernel<24, 12, false><<<NBKT, 512, 0, stream>>>(
        codes, bandoffs, dinv, bufB, b1, W2, nullptr, (float*)bufA, nullptr);
    // ---- layer 2 gather + layer-3 matmul fused: y3 [N,6] encoded ----
    gather_band_kernel<12, 6, false><<<NBKT, 512, 0, stream>>>(
        codes, bandoffs, dinv, bufA, b2, W3, nullptr, (float*)bufB, nullptr);
    // ---- layer 3 gather + layer-4 matmul fused: y4 [N,4] encoded ----
    gather_band_kernel<6, 4, false><<<NBKT, 512, 0, stream>>>(
        codes, bandoffs, dinv, bufB, b3, W4, nullptr, (float*)bufA, nullptr);
    // ---- layer 4 gather + layer-5 matmul fused: y5 [N,2] encoded ----
    gather_band_kernel<4, 2, false><<<NBKT, 512, 0, stream>>>(
        codes, bandoffs, dinv, bufA, b4, W5, nullptr, (float*)bufB, nullptr);
    // ---- layer 5 gather + classifier fused: out [N,4], h [N,2] (plain floats) ----
    gather_band_kernel<2, 4, true><<<NBKT, 512, 0, stream>>>(
        codes, bandoffs, dinv, bufB, b5, Wc, bc, out, out + (size_t)NN * 4);
}